// Round 18
// baseline (118.262 us; speedup 1.0000x reference)
//
#include <hip/hip_runtime.h>
#include <hip/hip_bf16.h>
#include <stdint.h>

typedef unsigned short u16;
typedef __attribute__((ext_vector_type(4))) float f32x4;
typedef __attribute__((ext_vector_type(8))) short bf16x8;

#define B_ 2
#define S_ 2048
#define H_ 16
#define D_ 1024
#define XELEMS (B_*S_*D_)      // 4194304 per tensor
#define WELEMS (D_*D_)         // 1048576 per weight
#define QSCALE 0.18033688f     // (1/8) * log2(e) — folded into Q at projection

__device__ __forceinline__ u16 f2bf(float f) {
  union { float f; unsigned u; } v; v.f = f;
  unsigned r = v.u + 0x7fffu + ((v.u >> 16) & 1u);
  return (u16)(r >> 16);
}

__device__ __forceinline__ void async16(const void* g, void* l) {
  __builtin_amdgcn_global_load_lds(
      (const __attribute__((address_space(1))) unsigned int*)g,
      (__attribute__((address_space(3))) unsigned int*)l, 16, 0, 0);
}

#if __has_builtin(__builtin_amdgcn_exp2f)
#define EXP2(x) __builtin_amdgcn_exp2f(x)
#else
#define EXP2(x) exp2f(x)
#endif

__device__ __forceinline__ unsigned cvtpk(float a, float b) {
  unsigned r;
  asm("v_cvt_pk_bf16_f32 %0, %1, %2" : "=v"(r) : "v"(a), "v"(b));
  return r;
}

// ---------------- prep: W transpose (blocks 0..4095) + X convert (4096..5119) ----
__global__ __launch_bounds__(256) void prep_k(
    const float* __restrict__ q, const float* __restrict__ k,
    const float* __restrict__ v,
    const float* __restrict__ Wq, const float* __restrict__ Wk,
    const float* __restrict__ Wv, const float* __restrict__ Wo,
    u16* __restrict__ X, u16* __restrict__ WT) {
  const int bid = blockIdx.x;
  if (bid < 4096) {
    __shared__ float tile[32][33];
    const int z = bid >> 10, rem = bid & 1023;
    const float* W = (z == 0) ? Wq : (z == 1) ? Wk : (z == 2) ? Wv : Wo;
    u16* o = WT + z * WELEMS;
    const int r0 = (rem >> 5) << 5, c0 = (rem & 31) << 5;
    const int tx = threadIdx.x & 31, ty = threadIdx.x >> 5;
    #pragma unroll
    for (int rr = ty; rr < 32; rr += 8)
      tile[rr][tx] = W[(r0 + rr) * D_ + c0 + tx];
    __syncthreads();
    #pragma unroll
    for (int rr = ty; rr < 32; rr += 8)
      o[(c0 + rr) * D_ + r0 + tx] = f2bf(tile[tx][rr]);
  } else {
    const int cb = bid - 4096;                 // 0..1023
    const int ngrp = XELEMS / 8;
    const int total = 3 * ngrp;
    for (int i = cb * 256 + threadIdx.x; i < total; i += 1024 * 256) {
      int which = i / ngrp;
      int off = (i - which * ngrp) * 8;
      const float* src = (which == 0) ? q : (which == 1) ? k : v;
      float4 a = *(const float4*)(src + off);
      float4 b = *(const float4*)(src + off + 4);
      u16 rr[8] = {f2bf(a.x), f2bf(a.y), f2bf(a.z), f2bf(a.w),
                   f2bf(b.x), f2bf(b.y), f2bf(b.z), f2bf(b.w)};
      uint4 pk;
      pk.x = (unsigned)rr[0] | ((unsigned)rr[1] << 16);
      pk.y = (unsigned)rr[2] | ((unsigned)rr[3] << 16);
      pk.z = (unsigned)rr[4] | ((unsigned)rr[5] << 16);
      pk.w = (unsigned)rr[6] | ((unsigned)rr[7] << 16);
      *(uint4*)(X + which * XELEMS + off) = pk;
    }
  }
}

// ---------------- GEMM: C[M,1024] = A[M,1024] @ BT^T + bias ----------------
// BK=64, XOR-swizzled LDS image. Shared memory is HOISTED to the caller and
// passed as a pointer so multiple template instantiations in one kernel
// share ONE allocation (r17 counters showed 2x34816=69632 LDS/block when
// gemm_body<0,0> and gemm_body<2,0> each declared their own static array,
// halving occupancy).
// DBUF=0: single-buffer (needs 34816B). DBUF=1: 2-phase dbuf vmcnt(8) (65536B).
// MODE 0: bf16 head-split [B,H,S,64] (scaled), LDS-transpose epilogue.
// MODE 1: f32 row-major. MODE 2: bf16 V^T [B,H,64,S], LDS-transpose epilogue.
template <int MODE, int DBUF>
__device__ __forceinline__ void gemm_body(char* __restrict__ smem,
                                          const u16* __restrict__ A,
                                          const u16* __restrict__ BT,
                                          const float* __restrict__ bias,
                                          void* __restrict__ outp,
                                          int bm, int bn, float scale) {
  const int tid = threadIdx.x;
  const int w = tid >> 6, l = tid & 63;
  const int wr = w >> 1, wc = w & 1;
  const int g = l >> 4, r = l & 15;
  (void)w; (void)l;

  f32x4 acc[4][4];
  #pragma unroll
  for (int i = 0; i < 4; i++)
    #pragma unroll
    for (int j = 0; j < 4; j++) acc[i][j] = (f32x4){0.f, 0.f, 0.f, 0.f};

  // staging: swizzled image in LDS, linear dest + pre-swizzled source
  int dst[4], aoff[4], boff[4];
  #pragma unroll
  for (int i = 0; i < 4; i++) {
    const int o = i * 4096 + tid * 16;         // byte offset in 16KB tile
    dst[i] = o;
    const int row = o >> 7;                    // 0..127
    const int cbyte = (o & 127) ^ ((row & 7) << 4);
    aoff[i] = (bm + row) * 1024 + (cbyte >> 1);
    boff[i] = (bn + row) * 1024 + (cbyte >> 1);
  }

  if (DBUF == 0) {
    char* Ab = smem;
    char* Bb = smem + 16384;
    for (int t = 0; t < 16; ++t) {
      const int k0 = t * 64;
      #pragma unroll
      for (int i = 0; i < 4; i++) async16(A + aoff[i] + k0, Ab + dst[i]);
      #pragma unroll
      for (int i = 0; i < 4; i++) async16(BT + boff[i] + k0, Bb + dst[i]);
      __syncthreads();
      bf16x8 af[2][4], bf[2][4];
      #pragma unroll
      for (int kk = 0; kk < 2; kk++)
        #pragma unroll
        for (int mi = 0; mi < 4; mi++) {
          const int rA = wr * 64 + mi * 16 + r;
          af[kk][mi] = *(const bf16x8*)(Ab +
              ((rA * 128 + kk * 64 + g * 16) ^ ((rA & 7) << 4)));
        }
      #pragma unroll
      for (int kk = 0; kk < 2; kk++)
        #pragma unroll
        for (int ni = 0; ni < 4; ni++) {
          const int rB = wc * 64 + ni * 16 + r;
          bf[kk][ni] = *(const bf16x8*)(Bb +
              ((rB * 128 + kk * 64 + g * 16) ^ ((rB & 7) << 4)));
        }
      #pragma unroll
      for (int kk = 0; kk < 2; kk++)
        #pragma unroll
        for (int mi = 0; mi < 4; mi++)
          #pragma unroll
          for (int ni = 0; ni < 4; ni++)
            acc[mi][ni] = __builtin_amdgcn_mfma_f32_16x16x32_bf16(
                af[kk][mi], bf[kk][ni], acc[mi][ni], 0, 0, 0);
      __syncthreads();
    }
  } else {
    #pragma unroll
    for (int i = 0; i < 4; i++) {
      async16(A + aoff[i], smem + dst[i]);
      async16(BT + boff[i], smem + 16384 + dst[i]);
    }
    for (int t = 0; t < 16; ++t) {
      const int buf = t & 1;
      const char* Ab = smem + buf * 32768;
      const char* Bb = Ab + 16384;
      if (t < 15) {
        const int k0 = (t + 1) * 64;
        char* An = smem + (buf ^ 1) * 32768;
        #pragma unroll
        for (int i = 0; i < 4; i++) {
          async16(A + aoff[i] + k0, An + dst[i]);
          async16(BT + boff[i] + k0, An + 16384 + dst[i]);
        }
        asm volatile("s_waitcnt vmcnt(8)" ::: "memory");   // tile t landed
      } else {
        asm volatile("s_waitcnt vmcnt(0)" ::: "memory");
      }
      asm volatile("s_barrier" ::: "memory");

      bf16x8 af[2][4], bf[2][4];
      #pragma unroll
      for (int kk = 0; kk < 2; kk++)
        #pragma unroll
        for (int mi = 0; mi < 4; mi++) {
          const int rA = wr * 64 + mi * 16 + r;
          af[kk][mi] = *(const bf16x8*)(Ab +
              ((rA * 128 + kk * 64 + g * 16) ^ ((rA & 7) << 4)));
        }
      #pragma unroll
      for (int kk = 0; kk < 2; kk++)
        #pragma unroll
        for (int ni = 0; ni < 4; ni++) {
          const int rB = wc * 64 + ni * 16 + r;
          bf[kk][ni] = *(const bf16x8*)(Bb +
              ((rB * 128 + kk * 64 + g * 16) ^ ((rB & 7) << 4)));
        }
      __builtin_amdgcn_s_setprio(1);
      #pragma unroll
      for (int kk = 0; kk < 2; kk++)
        #pragma unroll
        for (int mi = 0; mi < 4; mi++)
          #pragma unroll
          for (int ni = 0; ni < 4; ni++)
            acc[mi][ni] = __builtin_amdgcn_mfma_f32_16x16x32_bf16(
                af[kk][mi], bf[kk][ni], acc[mi][ni], 0, 0, 0);
      __builtin_amdgcn_s_setprio(0);
      asm volatile("s_barrier" ::: "memory");
    }
  }

  const int col0 = bn + wc * 64;
  float bc[4];
  #pragma unroll
  for (int ni = 0; ni < 4; ni++) bc[ni] = bias[col0 + ni * 16 + r];

  if (MODE == 0) {
    // ---- LDS transpose epilogue: Ts[row][col], stride 136 u16 ----
    u16* Ts = (u16*)smem;   // safe: K-loop ended with a full barrier
    #pragma unroll
    for (int mi = 0; mi < 4; mi++) {
      #pragma unroll
      for (int ni = 0; ni < 4; ni++) {
        const int lcol = wc * 64 + ni * 16 + r;
        #pragma unroll
        for (int i = 0; i < 4; i++) {
          const int lrow = wr * 64 + mi * 16 + g * 4 + i;
          Ts[lrow * 136 + lcol] = f2bf((acc[mi][ni][i] + bc[ni]) * scale);
        }
      }
    }
    __syncthreads();
    u16* out = (u16*)outp;
    const int bb = bm >> 11;           // batch (tile never crosses b)
    const int sbase = bm & 2047;
    #pragma unroll
    for (int j = 0; j < 8; j++) {
      const int c = j * 256 + tid;     // 0..2047 octet id
      const int row = c >> 4, oct = c & 15;
      const int col = bn + oct * 8;
      const int h = col >> 6, dk = col & 63;
      bf16x8 vv = *(const bf16x8*)&Ts[row * 136 + oct * 8];
      *(bf16x8*)&out[(((size_t)((bb << 4) | h) * 2048 + sbase + row) << 6) + dk] = vv;
    }
  } else if (MODE == 2) {
    // ---- LDS transpose epilogue: Ts[col][row], stride 136 u16 ----
    u16* Ts = (u16*)smem;   // safe: K-loop ended with a full barrier
    #pragma unroll
    for (int mi = 0; mi < 4; mi++) {
      const int lrow = wr * 64 + mi * 16 + g * 4;
      #pragma unroll
      for (int ni = 0; ni < 4; ni++) {
        const int lcol = wc * 64 + ni * 16 + r;
        u16 p0 = f2bf(acc[mi][ni][0] + bc[ni]);
        u16 p1 = f2bf(acc[mi][ni][1] + bc[ni]);
        u16 p2 = f2bf(acc[mi][ni][2] + bc[ni]);
        u16 p3 = f2bf(acc[mi][ni][3] + bc[ni]);
        uint2 pk;
        pk.x = (unsigned)p0 | ((unsigned)p1 << 16);
        pk.y = (unsigned)p2 | ((unsigned)p3 << 16);
        *(uint2*)&Ts[lcol * 136 + lrow] = pk;
      }
    }
    __syncthreads();
    u16* out = (u16*)outp;
    const int bb = bm >> 11;           // batch (tile never crosses b)
    const int sbase = bm & 2047;
    #pragma unroll
    for (int j = 0; j < 8; j++) {
      const int c = (tid >> 6) * 512 + j * 64 + (tid & 63);   // 0..2047
      const int dk = c >> 4, sc = c & 15;
      const int col = bn + dk;
      const int h = col >> 6, dkk = col & 63;
      bf16x8 vv = *(const bf16x8*)&Ts[dk * 136 + sc * 8];
      *(bf16x8*)&out[(((size_t)(((bb << 4) | h) * 64 + dkk)) << 11) +
                     sbase + sc * 8] = vv;
    }
  } else {
    float* out = (float*)outp;
    #pragma unroll
    for (int mi = 0; mi < 4; mi++) {
      const int row = bm + wr * 64 + mi * 16 + g * 4;
      #pragma unroll
      for (int ni = 0; ni < 4; ni++) {
        const int col = col0 + ni * 16 + r;
        #pragma unroll
        for (int i = 0; i < 4; i++)
          out[(row + i) * 1024 + col] = acc[mi][ni][i] + bc[ni];
      }
    }
  }
}

__global__ __launch_bounds__(256) void gemm_qkv_k(
    const u16* __restrict__ X, const u16* __restrict__ WT,
    const float* __restrict__ bq, const float* __restrict__ bk,
    const float* __restrict__ bv, u16* __restrict__ QKV) {
  __shared__ __align__(16) char smem[34816];   // ONE allocation for both paths
  const int z = blockIdx.z;
  const float* bias = (z == 0) ? bq : (z == 1) ? bk : bv;
  if (z == 2)
    gemm_body<2, 0>(smem, X + z * XELEMS, WT + z * WELEMS, bias,
                    QKV + z * XELEMS, blockIdx.x * 128, blockIdx.y * 128, 1.0f);
  else
    gemm_body<0, 0>(smem, X + z * XELEMS, WT + z * WELEMS, bias,
                    QKV + z * XELEMS, blockIdx.x * 128, blockIdx.y * 128,
                    (z == 0) ? QSCALE : 1.0f);
}

__global__ __launch_bounds__(256) void gemm_o_k(
    const u16* __restrict__ O, const u16* __restrict__ WOT,
    const float* __restrict__ bo, float* __restrict__ out) {
  __shared__ __align__(16) char smem[65536];
  gemm_body<1, 1>(smem, O, WOT, bo, out, blockIdx.x * 128, blockIdx.y * 128, 1.0f);
}

// ---------------- causal flash attention (v17: one barrier per step) --------
// Q/K: [B*H][S][64] bf16 (Q pre-scaled); V^T: [B*H][64][S] bf16.
// O: [B][S][H*64] bf16. Merged-pair, K 4-deep staged pre-barrier,
// V 3-deep staged post-barrier, single s_barrier per KV tile, counted
// vmcnt(3)/(2)/(0), shuffle-free steady-state softmax, cvt_pk P-pack.
__global__ __launch_bounds__(512) void attn_k(
    const u16* __restrict__ Qh, const u16* __restrict__ Kh,
    const u16* __restrict__ VTh, u16* __restrict__ O) {
  __shared__ __align__(16) char ldsK[4][8192];
  __shared__ __align__(16) char ldsV[3][8192];
  __shared__ __align__(16) u16 ldsP[8][16 * 72];

  const int bh = blockIdx.y;       // b*16 + h
  const int pj = blockIdx.x;       // pair index 0..15
  const int tid = threadIdx.x;
  const int w = tid >> 6, l = tid & 63;
  const int grp = w >> 2, wg = w & 3;
  const int g = l >> 4, r = l & 15;
  const int b = bh >> 4, h = bh & 15;
  const int pjx = b ? (15 - pj) : pj;   // complementary cost for co-resident pair

  const u16* Qp = Qh + bh * (S_ * 64);
  const char* Kp = (const char*)(Kh + bh * (S_ * 64));
  const char* Vp = (const char*)(VTh + bh * (64 * S_));

  // per-wave staging addresses (8 waves cover the 8KB tile)
  const int o = w * 1024 + l * 16;
  const int kdst = o;
  const int ksrc = o ^ (((o >> 7) & 7) << 4);
  const int vd = o >> 7, vcb = o & 127;
  const int vfix = vd * (S_ * 2) + (vcb ^ ((vd & 7) << 4));
  u16* Pq = &ldsP[w][0];

  const int qt = grp ? (31 - pjx) : pjx;
  const int q0w = qt * 64 + wg * 16;
  const int my_nt = qt + 1;
  const int nt_max = 32 - pjx;     // >= 17 always
  const int qloc = wg * 16 + r;

  bf16x8 qf[2];
  #pragma unroll
  for (int dh = 0; dh < 2; dh++)
    qf[dh] = *(const bf16x8*)(Qp + (q0w + r) * 64 + dh * 32 + g * 8);
  asm volatile("s_waitcnt vmcnt(0)" ::: "memory");  // Q in regs, counter clean

  f32x4 accT[4];
  #pragma unroll
  for (int dn = 0; dn < 4; dn++) accT[dn] = (f32x4){0.f, 0.f, 0.f, 0.f};
  float mrun = -1e30f, lsum = 0.f;    // lsum is a PER-LANE partial

  // prologue: stage tiles 0 and 1 (nt_max >= 17 so both always exist)
  async16(Kp + ksrc, &ldsK[0][0] + kdst);
  async16(Vp + vfix, &ldsV[0][0] + kdst);
  async16(Kp + 8192 + ksrc, &ldsK[1][0] + kdst);
  async16(Vp + 128 + vfix, &ldsV[1][0] + kdst);

  int kcur = 0, kpre = 2;          // K: t&3, (t+2)&3
  int vcur = 0, vpre = 2;          // V: t%3, (t+2)%3
  for (int t = 0; t < nt_max; ++t) {
    // K stage (pre-barrier; target last read at compute(t-2) — safe)
    if (t + 2 < nt_max) {
      async16(Kp + (t + 2) * 8192 + ksrc, &ldsK[kpre][0] + kdst);
      asm volatile("s_waitcnt vmcnt(3)" ::: "memory");   // K(t),V(t) landed
    } else if (t + 1 < nt_max) {
      asm volatile("s_waitcnt vmcnt(2)" ::: "memory");
    } else {
      asm volatile("s_waitcnt vmcnt(0)" ::: "memory");
    }
    asm volatile("s_barrier" ::: "memory");

    // V stage (post-barrier; target last read at PV(t-1) — safe at depth 3)
    if (t + 2 < nt_max)
      async16(Vp + (t + 2) * 128 + vfix, &ldsV[vpre][0] + kdst);

    if (t < my_nt) {
      // ---- QK^T (swapped) -> S^T[k][q=r], already in log2 units ----
      const char* Kb = &ldsK[kcur][0];
      f32x4 sc[4];
      #pragma unroll
      for (int ct = 0; ct < 4; ct++) {
        const int row = ct * 16 + r;
        const int sw = (row & 7) << 4;
        bf16x8 k0 = *(const bf16x8*)(Kb + ((row * 128 + g * 16) ^ sw));
        bf16x8 k1 = *(const bf16x8*)(Kb + ((row * 128 + 64 + g * 16) ^ sw));
        f32x4 z = (f32x4){0.f, 0.f, 0.f, 0.f};
        z = __builtin_amdgcn_mfma_f32_16x16x32_bf16(k0, qf[0], z, 0, 0, 0);
        sc[ct] = __builtin_amdgcn_mfma_f32_16x16x32_bf16(k1, qf[1], z, 0, 0, 0);
      }

      // ---- causal mask (diagonal tile only) ----
      if (t == my_nt - 1) {
        #pragma unroll
        for (int ct = 0; ct < 4; ct++)
          #pragma unroll
          for (int i = 0; i < 4; i++)
            if (ct * 16 + g * 4 + i > qloc) sc[ct][i] = -1e9f;
      }

      // ---- per-lane partial max (NO shuffles on the hot path) ----
      float a0 = fmaxf(fmaxf(sc[0][0], sc[0][1]), sc[0][2]);
      float a1 = fmaxf(fmaxf(sc[0][3], sc[1][0]), sc[1][1]);
      float a2 = fmaxf(fmaxf(sc[1][2], sc[1][3]), sc[2][0]);
      float a3 = fmaxf(fmaxf(sc[2][1], sc[2][2]), sc[2][3]);
      float a4 = fmaxf(fmaxf(sc[3][0], sc[3][1]), sc[3][2]);
      float pmax = fmaxf(fmaxf(fmaxf(a0, a1), fmaxf(a2, a3)),
                         fmaxf(a4, sc[3][3]));

      // ---- defer-max: exact cross-lane reduce only when triggered ----
      if (!__all(pmax - mrun <= 11.0f)) {
        float pm = fmaxf(pmax, __shfl_xor(pmax, 16, 64));
        pm = fmaxf(pm, __shfl_xor(pm, 32, 64));
        const float mnew = fmaxf(mrun, pm);
        const float corr = EXP2(mrun - mnew);
        mrun = mnew;
        #pragma unroll
        for (int dn = 0; dn < 4; dn++)
          #pragma unroll
          for (int i = 0; i < 4; i++) accT[dn][i] *= corr;
        lsum *= corr;
      }

      float ps = 0.f;
      #pragma unroll
      for (int ct = 0; ct < 4; ct++)
        #pragma unroll
        for (int i = 0; i < 4; i++) {
          const float p = EXP2(sc[ct][i] - mrun);
          sc[ct][i] = p;
          ps += p;
        }
      lsum += ps;    // per-lane partial; cross-lane reduce in epilogue

      // ---- pack P via v_cvt_pk_bf16_f32, store to per-wave LDS ----
      #pragma unroll
      for (int ct = 0; ct < 4; ct++) {
        uint2 pk;
        pk.x = cvtpk(sc[ct][0], sc[ct][1]);
        pk.y = cvtpk(sc[ct][2], sc[ct][3]);
        *(uint2*)&Pq[r * 72 + ct * 16 + g * 4] = pk;
      }
      asm volatile("s_waitcnt lgkmcnt(0)" ::: "memory");

      // ---- PV: O^T += V^T x P^T ----
      const char* Vb = &ldsV[vcur][0];
      bf16x8 pf[2];
      #pragma unroll
      for (int kp = 0; kp < 2; kp++)
        pf[kp] = *(const bf16x8*)&Pq[r * 72 + kp * 32 + g * 8];
      __builtin_amdgcn_s_setprio(1);
      #pragma unroll
      for (int dn = 0; dn < 4; dn++) {
        const int vrow = dn * 16 + r;
        const int vsw = (vrow & 7) << 4;
        #pragma unroll
        for (int kp = 0; kp < 2; kp++) {
          bf16x8 vf = *(const bf16x8*)(Vb + ((vrow * 128 + kp * 64 + g * 16) ^ vsw));
          accT[dn] = __builtin_amdgcn_mfma_f32_16x16x32_bf16(vf, pf[kp], accT[dn], 0, 0, 0);
        }
      }
      __builtin_amdgcn_s_setprio(0);
    }
    // NO end-of-body barrier (one rendezvous per step)
    kcur = (kcur + 1) & 3;
    kpre = (kpre + 1) & 3;
    vcur = (vcur == 2) ? 0 : vcur + 1;
    vpre = (vpre == 2) ? 0 : vpre + 1;
  }

  // ---- epilogue: reduce per-lane lsum partials across the row's 4 g-lanes ----
  float lrow = lsum + __shfl_xor(lsum, 16, 64);
  lrow = lrow + __shfl_xor(lrow, 32, 64);
  const float inv = 1.0f / lrow;
  const int qrow = q0w + r;
  #pragma unroll
  for (int dn = 0; dn < 4; dn++) {
    u16 o0 = f2bf(accT[dn][0] * inv), o1 = f2bf(accT[dn][1] * inv);
    u16 o2 = f2bf(accT[dn][2] * inv), o3 = f2bf(accT[dn][3] * inv);
    uint2 pk;
    pk.x = (unsigned)o0 | ((unsigned)o1 << 16);
    pk.y = (unsigned)o2 | ((unsigned)o3 << 16);
    *(uint2*)(O + ((size_t)(b * 2048 + qrow)) * 1024 + h * 64 + dn * 16 + g * 4) = pk;
  }
}

// ---------------- launcher ----------------
extern "C" void kernel_launch(void* const* d_in, const int* in_sizes, int n_in,
                              void* d_out, int out_size, void* d_ws, size_t ws_size,
                              hipStream_t stream) {
  const float* q  = (const float*)d_in[0];
  const float* k  = (const float*)d_in[1];
  const float* v  = (const float*)d_in[2];
  // d_in[3] = mask (causal triu) — applied analytically
  const float* Wq = (const float*)d_in[4];
  const float* bq = (const float*)d_in[5];
  const float* Wk = (const float*)d_in[6];
  const float* bk = (const float*)d_in[7];
  const float* Wv = (const float*)d_in[8];
  const float* bv = (const float*)d_in[9];
  const float* Wo = (const float*)d_in[10];
  const float* bo = (const float*)d_in[11];

  char* ws = (char*)d_ws;
  const size_t MB = 1u << 20;
  u16* X   = (u16*)(ws);             // 3 x XELEMS bf16 (24MB)
  u16* WT  = (u16*)(ws + 24 * MB);   // 4 x WELEMS bf16 (8MB)
  u16* QKV = (u16*)(ws + 32 * MB);   // Q,K: [B,H,S,64]; V^T: [B,H,64,S] (24MB)
  u16* O   = (u16*)(ws);             // reuse X region after projections

  hipLaunchKernelGGL(prep_k, dim3(5120), dim3(256), 0, stream,
                     q, k, v, Wq, Wk, Wv, Wo, X, WT);
  hipLaunchKernelGGL(gemm_qkv_k, dim3(32, 8, 3), dim3(256), 0, stream,
                     X, WT, bq, bk, bv, QKV);
  hipLaunchKernelGGL(attn_k, dim3(16, 32), dim3(512), 0, stream,
                     QKV, QKV + XELEMS, QKV + 2 * XELEMS, O);
  hipLaunchKernelGGL(gemm_o_k, dim3(32, 8), dim3(256), 0, stream,
                     O, WT + 3 * WELEMS, bo, (float*)d_out);
}

// Round 19
// 113.252 us; speedup vs baseline: 1.0442x; 1.0442x over previous
//
#include <hip/hip_runtime.h>
#include <hip/hip_bf16.h>
#include <stdint.h>

typedef unsigned short u16;
typedef __attribute__((ext_vector_type(4))) float f32x4;
typedef __attribute__((ext_vector_type(8))) short bf16x8;

#define B_ 2
#define S_ 2048
#define H_ 16
#define D_ 1024
#define XELEMS (B_*S_*D_)      // 4194304 per tensor
#define WELEMS (D_*D_)         // 1048576 per weight
#define QSCALE 0.18033688f     // (1/8) * log2(e) — folded into Q at projection

__device__ __forceinline__ u16 f2bf(float f) {
  union { float f; unsigned u; } v; v.f = f;
  unsigned r = v.u + 0x7fffu + ((v.u >> 16) & 1u);
  return (u16)(r >> 16);
}

__device__ __forceinline__ void async16(const void* g, void* l) {
  __builtin_amdgcn_global_load_lds(
      (const __attribute__((address_space(1))) unsigned int*)g,
      (__attribute__((address_space(3))) unsigned int*)l, 16, 0, 0);
}

#if __has_builtin(__builtin_amdgcn_exp2f)
#define EXP2(x) __builtin_amdgcn_exp2f(x)
#else
#define EXP2(x) exp2f(x)
#endif

__device__ __forceinline__ unsigned cvtpk(float a, float b) {
  unsigned r;
  asm("v_cvt_pk_bf16_f32 %0, %1, %2" : "=v"(r) : "v"(a), "v"(b));
  return r;
}

// ---------------- prep: W transpose (blocks 0..4095) + X convert (4096..5119) ----
__global__ __launch_bounds__(256) void prep_k(
    const float* __restrict__ q, const float* __restrict__ k,
    const float* __restrict__ v,
    const float* __restrict__ Wq, const float* __restrict__ Wk,
    const float* __restrict__ Wv, const float* __restrict__ Wo,
    u16* __restrict__ X, u16* __restrict__ WT) {
  const int bid = blockIdx.x;
  if (bid < 4096) {
    __shared__ float tile[32][33];
    const int z = bid >> 10, rem = bid & 1023;
    const float* W = (z == 0) ? Wq : (z == 1) ? Wk : (z == 2) ? Wv : Wo;
    u16* o = WT + z * WELEMS;
    const int r0 = (rem >> 5) << 5, c0 = (rem & 31) << 5;
    const int tx = threadIdx.x & 31, ty = threadIdx.x >> 5;
    #pragma unroll
    for (int rr = ty; rr < 32; rr += 8)
      tile[rr][tx] = W[(r0 + rr) * D_ + c0 + tx];
    __syncthreads();
    #pragma unroll
    for (int rr = ty; rr < 32; rr += 8)
      o[(c0 + rr) * D_ + r0 + tx] = f2bf(tile[tx][rr]);
  } else {
    const int cb = bid - 4096;                 // 0..1023
    const int ngrp = XELEMS / 8;
    const int total = 3 * ngrp;
    for (int i = cb * 256 + threadIdx.x; i < total; i += 1024 * 256) {
      int which = i / ngrp;
      int off = (i - which * ngrp) * 8;
      const float* src = (which == 0) ? q : (which == 1) ? k : v;
      float4 a = *(const float4*)(src + off);
      float4 b = *(const float4*)(src + off + 4);
      u16 rr[8] = {f2bf(a.x), f2bf(a.y), f2bf(a.z), f2bf(a.w),
                   f2bf(b.x), f2bf(b.y), f2bf(b.z), f2bf(b.w)};
      uint4 pk;
      pk.x = (unsigned)rr[0] | ((unsigned)rr[1] << 16);
      pk.y = (unsigned)rr[2] | ((unsigned)rr[3] << 16);
      pk.z = (unsigned)rr[4] | ((unsigned)rr[5] << 16);
      pk.w = (unsigned)rr[6] | ((unsigned)rr[7] << 16);
      *(uint4*)(X + which * XELEMS + off) = pk;
    }
  }
}

// ---------------- GEMM: C[M,1024] = A[M,1024] @ BT^T + bias ----------------
// smem hoisted to caller (one allocation per kernel).
// PIPE=0 (qkv): BK=32, 3-deep buffers, single barrier/step, POST-barrier
//   staging of tile t+2, counted vmcnt(4) — v17-attn pattern; loads never
//   drained in-loop. 48KB -> 3 blocks/CU. Fragments bijective on 1KB ->
//   conflict-free with LINEAR LDS (no swizzle either side).
// PIPE=1 (gemm_o): BK=64 2-phase dbuf w/ vmcnt(8) (unchanged, 64KB).
// MODE 0: bf16 head-split [B,H,S,64] (scaled), LDS-transpose epilogue.
// MODE 1: f32 row-major. MODE 2: bf16 V^T [B,H,64,S], LDS-transpose epilogue.
template <int MODE, int PIPE>
__device__ __forceinline__ void gemm_body(char* __restrict__ smem,
                                          const u16* __restrict__ A,
                                          const u16* __restrict__ BT,
                                          const float* __restrict__ bias,
                                          void* __restrict__ outp,
                                          int bm, int bn, float scale) {
  const int tid = threadIdx.x;
  const int w = tid >> 6, l = tid & 63;
  const int wr = w >> 1, wc = w & 1;
  const int g = l >> 4, r = l & 15;
  (void)w; (void)l;

  f32x4 acc[4][4];
  #pragma unroll
  for (int i = 0; i < 4; i++)
    #pragma unroll
    for (int j = 0; j < 4; j++) acc[i][j] = (f32x4){0.f, 0.f, 0.f, 0.f};

  if (PIPE == 0) {
    // ---- BK=32, 3-deep, single barrier per step (v17 pattern) ----
    // per-thread staging chunks: A-tile 8KB, B-tile 8KB, 2+2 chunks of 16B
    int dst[2], aoff[2], boff[2];
    #pragma unroll
    for (int i = 0; i < 2; i++) {
      const int o = i * 4096 + tid * 16;       // byte offset in 8KB tile
      dst[i] = o;
      const int row = o >> 6;                  // 64B rows (BK=32 bf16)
      const int cb = o & 63;
      aoff[i] = (bm + row) * 1024 + (cb >> 1);
      boff[i] = (bn + row) * 1024 + (cb >> 1);
    }
    // prologue: stage K-tiles 0 and 1 into bufs 0,1
    #pragma unroll
    for (int i = 0; i < 2; i++) {
      async16(A + aoff[i], smem + dst[i]);
      async16(BT + boff[i], smem + 8192 + dst[i]);
    }
    #pragma unroll
    for (int i = 0; i < 2; i++) {
      async16(A + aoff[i] + 32, smem + 16384 + dst[i]);
      async16(BT + boff[i] + 32, smem + 16384 + 8192 + dst[i]);
    }

    for (int t = 0; t < 32; ++t) {
      if (t + 2 < 32) {
        asm volatile("s_waitcnt vmcnt(4)" ::: "memory");   // tile t landed
      } else {
        asm volatile("s_waitcnt vmcnt(0)" ::: "memory");
      }
      asm volatile("s_barrier" ::: "memory");

      // post-barrier stage of tile t+2 into buf (t+2)%3 (readers done)
      if (t + 2 < 32) {
        const int p2 = (t + 2) % 3;
        const int k0 = (t + 2) * 32;
        char* Bu = smem + p2 * 16384;
        #pragma unroll
        for (int i = 0; i < 2; i++) {
          async16(A + aoff[i] + k0, Bu + dst[i]);
          async16(BT + boff[i] + k0, Bu + 8192 + dst[i]);
        }
      }

      const char* Ab = smem + (t % 3) * 16384;
      const char* Bb = Ab + 8192;
      bf16x8 af[4], bf[4];
      #pragma unroll
      for (int mi = 0; mi < 4; mi++)
        af[mi] = *(const bf16x8*)(Ab + ((wr * 64 + mi * 16 + r) * 64 + g * 16));
      #pragma unroll
      for (int ni = 0; ni < 4; ni++)
        bf[ni] = *(const bf16x8*)(Bb + ((wc * 64 + ni * 16 + r) * 64 + g * 16));
      __builtin_amdgcn_s_setprio(1);
      #pragma unroll
      for (int mi = 0; mi < 4; mi++)
        #pragma unroll
        for (int ni = 0; ni < 4; ni++)
          acc[mi][ni] = __builtin_amdgcn_mfma_f32_16x16x32_bf16(
              af[mi], bf[ni], acc[mi][ni], 0, 0, 0);
      __builtin_amdgcn_s_setprio(0);
    }
  } else {
    // ---- BK=64, XOR-swizzled, 2-phase dbuf w/ vmcnt(8) (unchanged) ----
    int dst[4], aoff[4], boff[4];
    #pragma unroll
    for (int i = 0; i < 4; i++) {
      const int o = i * 4096 + tid * 16;       // byte offset in 16KB tile
      dst[i] = o;
      const int row = o >> 7;                  // 0..127
      const int cbyte = (o & 127) ^ ((row & 7) << 4);
      aoff[i] = (bm + row) * 1024 + (cbyte >> 1);
      boff[i] = (bn + row) * 1024 + (cbyte >> 1);
    }
    #pragma unroll
    for (int i = 0; i < 4; i++) {
      async16(A + aoff[i], smem + dst[i]);
      async16(BT + boff[i], smem + 16384 + dst[i]);
    }
    for (int t = 0; t < 16; ++t) {
      const int buf = t & 1;
      const char* Ab = smem + buf * 32768;
      const char* Bb = Ab + 16384;
      if (t < 15) {
        const int k0 = (t + 1) * 64;
        char* An = smem + (buf ^ 1) * 32768;
        #pragma unroll
        for (int i = 0; i < 4; i++) {
          async16(A + aoff[i] + k0, An + dst[i]);
          async16(BT + boff[i] + k0, An + 16384 + dst[i]);
        }
        asm volatile("s_waitcnt vmcnt(8)" ::: "memory");   // tile t landed
      } else {
        asm volatile("s_waitcnt vmcnt(0)" ::: "memory");
      }
      asm volatile("s_barrier" ::: "memory");

      bf16x8 af[2][4], bf[2][4];
      #pragma unroll
      for (int kk = 0; kk < 2; kk++)
        #pragma unroll
        for (int mi = 0; mi < 4; mi++) {
          const int rA = wr * 64 + mi * 16 + r;
          af[kk][mi] = *(const bf16x8*)(Ab +
              ((rA * 128 + kk * 64 + g * 16) ^ ((rA & 7) << 4)));
        }
      #pragma unroll
      for (int kk = 0; kk < 2; kk++)
        #pragma unroll
        for (int ni = 0; ni < 4; ni++) {
          const int rB = wc * 64 + ni * 16 + r;
          bf[kk][ni] = *(const bf16x8*)(Bb +
              ((rB * 128 + kk * 64 + g * 16) ^ ((rB & 7) << 4)));
        }
      __builtin_amdgcn_s_setprio(1);
      #pragma unroll
      for (int kk = 0; kk < 2; kk++)
        #pragma unroll
        for (int mi = 0; mi < 4; mi++)
          #pragma unroll
          for (int ni = 0; ni < 4; ni++)
            acc[mi][ni] = __builtin_amdgcn_mfma_f32_16x16x32_bf16(
                af[kk][mi], bf[kk][ni], acc[mi][ni], 0, 0, 0);
      __builtin_amdgcn_s_setprio(0);
      asm volatile("s_barrier" ::: "memory");
    }
  }

  const int col0 = bn + wc * 64;
  float bc[4];
  #pragma unroll
  for (int ni = 0; ni < 4; ni++) bc[ni] = bias[col0 + ni * 16 + r];

  if (MODE == 0) {
    __syncthreads();   // PIPE=0 loop doesn't end with a barrier; protect smem reuse
    // ---- LDS transpose epilogue: Ts[row][col], stride 136 u16 ----
    u16* Ts = (u16*)smem;
    #pragma unroll
    for (int mi = 0; mi < 4; mi++) {
      #pragma unroll
      for (int ni = 0; ni < 4; ni++) {
        const int lcol = wc * 64 + ni * 16 + r;
        #pragma unroll
        for (int i = 0; i < 4; i++) {
          const int lrow = wr * 64 + mi * 16 + g * 4 + i;
          Ts[lrow * 136 + lcol] = f2bf((acc[mi][ni][i] + bc[ni]) * scale);
        }
      }
    }
    __syncthreads();
    u16* out = (u16*)outp;
    const int bb = bm >> 11;           // batch (tile never crosses b)
    const int sbase = bm & 2047;
    #pragma unroll
    for (int j = 0; j < 8; j++) {
      const int c = j * 256 + tid;     // 0..2047 octet id
      const int row = c >> 4, oct = c & 15;
      const int col = bn + oct * 8;
      const int h = col >> 6, dk = col & 63;
      bf16x8 vv = *(const bf16x8*)&Ts[row * 136 + oct * 8];
      *(bf16x8*)&out[(((size_t)((bb << 4) | h) * 2048 + sbase + row) << 6) + dk] = vv;
    }
  } else if (MODE == 2) {
    __syncthreads();
    // ---- LDS transpose epilogue: Ts[col][row], stride 136 u16 ----
    u16* Ts = (u16*)smem;
    #pragma unroll
    for (int mi = 0; mi < 4; mi++) {
      const int lrow = wr * 64 + mi * 16 + g * 4;
      #pragma unroll
      for (int ni = 0; ni < 4; ni++) {
        const int lcol = wc * 64 + ni * 16 + r;
        u16 p0 = f2bf(acc[mi][ni][0] + bc[ni]);
        u16 p1 = f2bf(acc[mi][ni][1] + bc[ni]);
        u16 p2 = f2bf(acc[mi][ni][2] + bc[ni]);
        u16 p3 = f2bf(acc[mi][ni][3] + bc[ni]);
        uint2 pk;
        pk.x = (unsigned)p0 | ((unsigned)p1 << 16);
        pk.y = (unsigned)p2 | ((unsigned)p3 << 16);
        *(uint2*)&Ts[lcol * 136 + lrow] = pk;
      }
    }
    __syncthreads();
    u16* out = (u16*)outp;
    const int bb = bm >> 11;           // batch (tile never crosses b)
    const int sbase = bm & 2047;
    #pragma unroll
    for (int j = 0; j < 8; j++) {
      const int c = (tid >> 6) * 512 + j * 64 + (tid & 63);   // 0..2047
      const int dk = c >> 4, sc = c & 15;
      const int col = bn + dk;
      const int h = col >> 6, dkk = col & 63;
      bf16x8 vv = *(const bf16x8*)&Ts[dk * 136 + sc * 8];
      *(bf16x8*)&out[(((size_t)(((bb << 4) | h) * 64 + dkk)) << 11) +
                     sbase + sc * 8] = vv;
    }
  } else {
    float* out = (float*)outp;
    #pragma unroll
    for (int mi = 0; mi < 4; mi++) {
      const int row = bm + wr * 64 + mi * 16 + g * 4;
      #pragma unroll
      for (int ni = 0; ni < 4; ni++) {
        const int col = col0 + ni * 16 + r;
        #pragma unroll
        for (int i = 0; i < 4; i++)
          out[(row + i) * 1024 + col] = acc[mi][ni][i] + bc[ni];
      }
    }
  }
}

__global__ __launch_bounds__(256) void gemm_qkv_k(
    const u16* __restrict__ X, const u16* __restrict__ WT,
    const float* __restrict__ bq, const float* __restrict__ bk,
    const float* __restrict__ bv, u16* __restrict__ QKV) {
  __shared__ __align__(16) char smem[49152];   // 3x16KB pipeline; epilogue reuse
  const int z = blockIdx.z;
  const float* bias = (z == 0) ? bq : (z == 1) ? bk : bv;
  if (z == 2)
    gemm_body<2, 0>(smem, X + z * XELEMS, WT + z * WELEMS, bias,
                    QKV + z * XELEMS, blockIdx.x * 128, blockIdx.y * 128, 1.0f);
  else
    gemm_body<0, 0>(smem, X + z * XELEMS, WT + z * WELEMS, bias,
                    QKV + z * XELEMS, blockIdx.x * 128, blockIdx.y * 128,
                    (z == 0) ? QSCALE : 1.0f);
}

__global__ __launch_bounds__(256) void gemm_o_k(
    const u16* __restrict__ O, const u16* __restrict__ WOT,
    const float* __restrict__ bo, float* __restrict__ out) {
  __shared__ __align__(16) char smem[65536];
  gemm_body<1, 1>(smem, O, WOT, bo, out, blockIdx.x * 128, blockIdx.y * 128, 1.0f);
}

// ---------------- causal flash attention (v17: one barrier per step) --------
// Q/K: [B*H][S][64] bf16 (Q pre-scaled); V^T: [B*H][64][S] bf16.
// O: [B][S][H*64] bf16. Merged-pair, K 4-deep staged pre-barrier,
// V 3-deep staged post-barrier, single s_barrier per KV tile, counted
// vmcnt(3)/(2)/(0), shuffle-free steady-state softmax, cvt_pk P-pack.
__global__ __launch_bounds__(512) void attn_k(
    const u16* __restrict__ Qh, const u16* __restrict__ Kh,
    const u16* __restrict__ VTh, u16* __restrict__ O) {
  __shared__ __align__(16) char ldsK[4][8192];
  __shared__ __align__(16) char ldsV[3][8192];
  __shared__ __align__(16) u16 ldsP[8][16 * 72];

  const int bh = blockIdx.y;       // b*16 + h
  const int pj = blockIdx.x;       // pair index 0..15
  const int tid = threadIdx.x;
  const int w = tid >> 6, l = tid & 63;
  const int grp = w >> 2, wg = w & 3;
  const int g = l >> 4, r = l & 15;
  const int b = bh >> 4, h = bh & 15;
  const int pjx = b ? (15 - pj) : pj;   // complementary cost for co-resident pair

  const u16* Qp = Qh + bh * (S_ * 64);
  const char* Kp = (const char*)(Kh + bh * (S_ * 64));
  const char* Vp = (const char*)(VTh + bh * (64 * S_));

  // per-wave staging addresses (8 waves cover the 8KB tile)
  const int o = w * 1024 + l * 16;
  const int kdst = o;
  const int ksrc = o ^ (((o >> 7) & 7) << 4);
  const int vd = o >> 7, vcb = o & 127;
  const int vfix = vd * (S_ * 2) + (vcb ^ ((vd & 7) << 4));
  u16* Pq = &ldsP[w][0];

  const int qt = grp ? (31 - pjx) : pjx;
  const int q0w = qt * 64 + wg * 16;
  const int my_nt = qt + 1;
  const int nt_max = 32 - pjx;     // >= 17 always
  const int qloc = wg * 16 + r;

  bf16x8 qf[2];
  #pragma unroll
  for (int dh = 0; dh < 2; dh++)
    qf[dh] = *(const bf16x8*)(Qp + (q0w + r) * 64 + dh * 32 + g * 8);
  asm volatile("s_waitcnt vmcnt(0)" ::: "memory");  // Q in regs, counter clean

  f32x4 accT[4];
  #pragma unroll
  for (int dn = 0; dn < 4; dn++) accT[dn] = (f32x4){0.f, 0.f, 0.f, 0.f};
  float mrun = -1e30f, lsum = 0.f;    // lsum is a PER-LANE partial

  // prologue: stage tiles 0 and 1 (nt_max >= 17 so both always exist)
  async16(Kp + ksrc, &ldsK[0][0] + kdst);
  async16(Vp + vfix, &ldsV[0][0] + kdst);
  async16(Kp + 8192 + ksrc, &ldsK[1][0] + kdst);
  async16(Vp + 128 + vfix, &ldsV[1][0] + kdst);

  int kcur = 0, kpre = 2;          // K: t&3, (t+2)&3
  int vcur = 0, vpre = 2;          // V: t%3, (t+2)%3
  for (int t = 0; t < nt_max; ++t) {
    // K stage (pre-barrier; target last read at compute(t-2) — safe)
    if (t + 2 < nt_max) {
      async16(Kp + (t + 2) * 8192 + ksrc, &ldsK[kpre][0] + kdst);
      asm volatile("s_waitcnt vmcnt(3)" ::: "memory");   // K(t),V(t) landed
    } else if (t + 1 < nt_max) {
      asm volatile("s_waitcnt vmcnt(2)" ::: "memory");
    } else {
      asm volatile("s_waitcnt vmcnt(0)" ::: "memory");
    }
    asm volatile("s_barrier" ::: "memory");

    // V stage (post-barrier; target last read at PV(t-1) — safe at depth 3)
    if (t + 2 < nt_max)
      async16(Vp + (t + 2) * 128 + vfix, &ldsV[vpre][0] + kdst);

    if (t < my_nt) {
      // ---- QK^T (swapped) -> S^T[k][q=r], already in log2 units ----
      const char* Kb = &ldsK[kcur][0];
      f32x4 sc[4];
      #pragma unroll
      for (int ct = 0; ct < 4; ct++) {
        const int row = ct * 16 + r;
        const int sw = (row & 7) << 4;
        bf16x8 k0 = *(const bf16x8*)(Kb + ((row * 128 + g * 16) ^ sw));
        bf16x8 k1 = *(const bf16x8*)(Kb + ((row * 128 + 64 + g * 16) ^ sw));
        f32x4 z = (f32x4){0.f, 0.f, 0.f, 0.f};
        z = __builtin_amdgcn_mfma_f32_16x16x32_bf16(k0, qf[0], z, 0, 0, 0);
        sc[ct] = __builtin_amdgcn_mfma_f32_16x16x32_bf16(k1, qf[1], z, 0, 0, 0);
      }

      // ---- causal mask (diagonal tile only) ----
      if (t == my_nt - 1) {
        #pragma unroll
        for (int ct = 0; ct < 4; ct++)
          #pragma unroll
          for (int i = 0; i < 4; i++)
            if (ct * 16 + g * 4 + i > qloc) sc[ct][i] = -1e9f;
      }

      // ---- per-lane partial max (NO shuffles on the hot path) ----
      float a0 = fmaxf(fmaxf(sc[0][0], sc[0][1]), sc[0][2]);
      float a1 = fmaxf(fmaxf(sc[0][3], sc[1][0]), sc[1][1]);
      float a2 = fmaxf(fmaxf(sc[1][2], sc[1][3]), sc[2][0]);
      float a3 = fmaxf(fmaxf(sc[2][1], sc[2][2]), sc[2][3]);
      float a4 = fmaxf(fmaxf(sc[3][0], sc[3][1]), sc[3][2]);
      float pmax = fmaxf(fmaxf(fmaxf(a0, a1), fmaxf(a2, a3)),
                         fmaxf(a4, sc[3][3]));

      // ---- defer-max: exact cross-lane reduce only when triggered ----
      if (!__all(pmax - mrun <= 11.0f)) {
        float pm = fmaxf(pmax, __shfl_xor(pmax, 16, 64));
        pm = fmaxf(pm, __shfl_xor(pm, 32, 64));
        const float mnew = fmaxf(mrun, pm);
        const float corr = EXP2(mrun - mnew);
        mrun = mnew;
        #pragma unroll
        for (int dn = 0; dn < 4; dn++)
          #pragma unroll
          for (int i = 0; i < 4; i++) accT[dn][i] *= corr;
        lsum *= corr;
      }

      float ps = 0.f;
      #pragma unroll
      for (int ct = 0; ct < 4; ct++)
        #pragma unroll
        for (int i = 0; i < 4; i++) {
          const float p = EXP2(sc[ct][i] - mrun);
          sc[ct][i] = p;
          ps += p;
        }
      lsum += ps;    // per-lane partial; cross-lane reduce in epilogue

      // ---- pack P via v_cvt_pk_bf16_f32, store to per-wave LDS ----
      #pragma unroll
      for (int ct = 0; ct < 4; ct++) {
        uint2 pk;
        pk.x = cvtpk(sc[ct][0], sc[ct][1]);
        pk.y = cvtpk(sc[ct][2], sc[ct][3]);
        *(uint2*)&Pq[r * 72 + ct * 16 + g * 4] = pk;
      }
      asm volatile("s_waitcnt lgkmcnt(0)" ::: "memory");

      // ---- PV: O^T += V^T x P^T ----
      const char* Vb = &ldsV[vcur][0];
      bf16x8 pf[2];
      #pragma unroll
      for (int kp = 0; kp < 2; kp++)
        pf[kp] = *(const bf16x8*)&Pq[r * 72 + kp * 32 + g * 8];
      __builtin_amdgcn_s_setprio(1);
      #pragma unroll
      for (int dn = 0; dn < 4; dn++) {
        const int vrow = dn * 16 + r;
        const int vsw = (vrow & 7) << 4;
        #pragma unroll
        for (int kp = 0; kp < 2; kp++) {
          bf16x8 vf = *(const bf16x8*)(Vb + ((vrow * 128 + kp * 64 + g * 16) ^ vsw));
          accT[dn] = __builtin_amdgcn_mfma_f32_16x16x32_bf16(vf, pf[kp], accT[dn], 0, 0, 0);
        }
      }
      __builtin_amdgcn_s_setprio(0);
    }
    // NO end-of-body barrier (one rendezvous per step)
    kcur = (kcur + 1) & 3;
    kpre = (kpre + 1) & 3;
    vcur = (vcur == 2) ? 0 : vcur + 1;
    vpre = (vpre == 2) ? 0 : vpre + 1;
  }

  // ---- epilogue: reduce per-lane lsum partials across the row's 4 g-lanes ----
  float lrow = lsum + __shfl_xor(lsum, 16, 64);
  lrow = lrow + __shfl_xor(lrow, 32, 64);
  const float inv = 1.0f / lrow;
  const int qrow = q0w + r;
  #pragma unroll
  for (int dn = 0; dn < 4; dn++) {
    u16 o0 = f2bf(accT[dn][0] * inv), o1 = f2bf(accT[dn][1] * inv);
    u16 o2 = f2bf(accT[dn][2] * inv), o3 = f2bf(accT[dn][3] * inv);
    uint2 pk;
    pk.x = (unsigned)o0 | ((unsigned)o1 << 16);
    pk.y = (unsigned)o2 | ((unsigned)o3 << 16);
    *(uint2*)(O + ((size_t)(b * 2048 + qrow)) * 1024 + h * 64 + dn * 16 + g * 4) = pk;
  }
}

// ---------------- launcher ----------------
extern "C" void kernel_launch(void* const* d_in, const int* in_sizes, int n_in,
                              void* d_out, int out_size, void* d_ws, size_t ws_size,
                              hipStream_t stream) {
  const float* q  = (const float*)d_in[0];
  const float* k  = (const float*)d_in[1];
  const float* v  = (const float*)d_in[2];
  // d_in[3] = mask (causal triu) — applied analytically
  const float* Wq = (const float*)d_in[4];
  const float* bq = (const float*)d_in[5];
  const float* Wk = (const float*)d_in[6];
  const float* bk = (const float*)d_in[7];
  const float* Wv = (const float*)d_in[8];
  const float* bv = (const float*)d_in[9];
  const float* Wo = (const float*)d_in[10];
  const float* bo = (const float*)d_in[11];

  char* ws = (char*)d_ws;
  const size_t MB = 1u << 20;
  u16* X   = (u16*)(ws);             // 3 x XELEMS bf16 (24MB)
  u16* WT  = (u16*)(ws + 24 * MB);   // 4 x WELEMS bf16 (8MB)
  u16* QKV = (u16*)(ws + 32 * MB);   // Q,K: [B,H,S,64]; V^T: [B,H,64,S] (24MB)
  u16* O   = (u16*)(ws);             // reuse X region after projections

  hipLaunchKernelGGL(prep_k, dim3(5120), dim3(256), 0, stream,
                     q, k, v, Wq, Wk, Wv, Wo, X, WT);
  hipLaunchKernelGGL(gemm_qkv_k, dim3(32, 8, 3), dim3(256), 0, stream,
                     X, WT, bq, bk, bv, QKV);
  hipLaunchKernelGGL(attn_k, dim3(16, 32), dim3(512), 0, stream,
                     QKV, QKV + XELEMS, QKV + 2 * XELEMS, O);
  hipLaunchKernelGGL(gemm_o_k, dim3(32, 8), dim3(256), 0, stream,
                     O, WT + 3 * WELEMS, bo, (float*)d_out);
}